// Round 3
// baseline (54.283 us; speedup 1.0000x reference)
//
#include <hip/hip_runtime.h>

// ContinuousWaveletTransform on MI355X — (4, 4096) fp32 -> (4, 32, 4096) complex64.
//
// Math: the reference wavelet is NOT dilated by scale: env = exp(-0.5*k^2) with
// k in raw samples underflows fp32 by k=13, and nrm = max|w| = 1 (at k=0), so
// every scale shares the same 13-tap wavelet. Scale only sets the shift wl_s:
//   out[b,s,n] = sum_{k=0}^{12} w[k] * signal[b, n - wl_s + k]   (zero-padded)
// wl table = min(2048, 64 + 4032*s/31) (exact integer identity of the host
// table, all even, all >= 64 > KTAPS so only the j >= 0 bound can bind).
//
// R1/R2 post-mortem: loads were provably in-bounds yet both kernels aborted ->
// the 4 MB unconditional float2 store to d_out is the remaining suspect (the
// complex64 output may be allocated as prod(shape)=524288 floats = 2 MB).
// This round: every store is guarded by out_size (float element count) and the
// kernel adapts: out_size==2*N -> interleaved (re,im); out_size==N -> re only.
// No byte beyond out_size*4 is ever written.

#define NSCALES 32
#define SIGLEN  4096
#define NBATCH  4
#define KTAPS   13
#define NCPLX   (NBATCH * NSCALES * SIGLEN)   // 524288 complex outputs

// w_re[k] = exp(-0.5 k^2) * cos(pi k / 3), w_im[k] = exp(-0.5 k^2) * sin(pi k / 3)
constexpr float WRE[KTAPS] = {
     1.0f,
     0.30326532985631671f,
    -0.067667641618306351f,
    -0.011108996538242306f,
    -1.6773131395125593e-04f,
     1.8633265860393356e-06f,
     1.5229979744712629e-08f,
     1.1448674228095576e-11f,
    -6.3320827745470882e-15f,
    -2.5767571091549811e-18f,
    -9.6437492398195889e-23f,
     2.6555457487024766e-27f,
     5.3801861600211382e-32f
};

constexpr float WIM[KTAPS] = {
     0.0f,
     0.52527095940951546f,
     0.11720379540754518f,
     0.0f,
    -2.9051958683798235e-04f,
    -3.2273763459803839e-06f,
     0.0f,
     1.9829656626983019e-11f,
     1.0967474900693360e-14f,
     0.0f,
    -1.6703459536984179e-22f,
    -4.5995743893035117e-27f,
     0.0f
};

__global__ __launch_bounds__(256)
void cwt_kernel(const float* __restrict__ sig, float* __restrict__ out,
                const int out_size, const int interleaved) {
    const int c = blockIdx.x * blockDim.x + threadIdx.x;   // complex index
    if (c >= NCPLX) return;

    const int n  = c & (SIGLEN - 1);
    const int bs = c >> 12;            // b*NSCALES + s
    const int s  = bs & (NSCALES - 1);
    const int b  = bs >> 5;

    // wl = min(2048, 64 + 4032*s/31) — exact match of the host table, all even.
    const int wl = min(2048, 64 + (4032 * s) / 31);

    const float* __restrict__ sb = sig + b * SIGLEN;
    const int base = n - wl;

    float re = 0.0f, im = 0.0f;
#pragma unroll
    for (int k = 0; k < KTAPS; ++k) {
        const int j = base + k;
        const int jc = j < 0 ? 0 : j;          // address always in [0, SIGLEN)
        float x = sb[jc];                      // upper bound never binds: wl >= 64 > KTAPS
        x = (j < 0) ? 0.0f : x;                // zero the VALUE, not the address
        re = fmaf(WRE[k], x, re);
        im = fmaf(WIM[k], x, im);
    }

    if (interleaved) {
        const int f = 2 * c;
        if (f + 1 < out_size) {                // guarded: never write past out_size floats
            out[f]     = re;
            out[f + 1] = im;
        }
    } else {
        if (c < out_size) {
            out[c] = re;                       // real-part-only layout
        }
    }
}

extern "C" void kernel_launch(void* const* d_in, const int* in_sizes, int n_in,
                              void* d_out, int out_size, void* d_ws, size_t ws_size,
                              hipStream_t stream) {
    const float* sig = (const float*)d_in[0];
    float* out = (float*)d_out;

    const int interleaved = (out_size >= 2 * NCPLX) ? 1 : 0;

    const int block = 256;
    const int grid = (NCPLX + block - 1) / block;   // 2048 blocks

    cwt_kernel<<<grid, block, 0, stream>>>(sig, out, out_size, interleaved);
}

// Round 6
// 53.536 us; speedup vs baseline: 1.0140x; 1.0140x over previous
//
#include <hip/hip_runtime.h>

// ContinuousWaveletTransform on MI355X — (4, 4096) fp32 -> (4, 32, 4096) complex64.
//
// Math: the reference wavelet is NOT dilated by scale: env = exp(-0.5*k^2) with
// k in raw samples underflows fp32 by k=13, and nrm = max|w| = 1 (at k=0), so
// every scale shares the same 13-tap wavelet. Scale only sets the shift wl_s:
//   out[b,s,n] = sum_{k=0}^{12} w[k] * signal[b, n - wl_s + k]   (zero-padded)
// wl table = min(2048, 64 + 4032*s/31) (exact integer identity of the host
// table, all even, all >= 64 > KTAPS so only the j >= 0 bound can bind).
//
// History: this EXACT kernel passed in R3 (absmax 0.00390625, dur_us 54.28;
// profile showed the timed window is dominated by the harness's 40 us / 268 MB
// workspace poison fills at 83% HBM peak — the kernel itself is single-digit
// us). R4 (float4 4-per-thread) and R5 (float2 store, otherwise identical to
// this) BOTH failed with the bit-identical absmax 6.203125e+00 — two different
// kernels, one error value — implicating a stale binary or a vector-store
// readback artifact, not the math. Reverting verbatim to the known-good
// scalar-store structure.

#define NSCALES 32
#define SIGLEN  4096
#define NBATCH  4
#define KTAPS   13
#define NCPLX   (NBATCH * NSCALES * SIGLEN)   // 524288 complex outputs

// w_re[k] = exp(-0.5 k^2) * cos(pi k / 3), w_im[k] = exp(-0.5 k^2) * sin(pi k / 3)
constexpr float WRE[KTAPS] = {
     1.0f,
     0.30326532985631671f,
    -0.067667641618306351f,
    -0.011108996538242306f,
    -1.6773131395125593e-04f,
     1.8633265860393356e-06f,
     1.5229979744712629e-08f,
     1.1448674228095576e-11f,
    -6.3320827745470882e-15f,
    -2.5767571091549811e-18f,
    -9.6437492398195889e-23f,
     2.6555457487024766e-27f,
     5.3801861600211382e-32f
};

constexpr float WIM[KTAPS] = {
     0.0f,
     0.52527095940951546f,
     0.11720379540754518f,
     0.0f,
    -2.9051958683798235e-04f,
    -3.2273763459803839e-06f,
     0.0f,
     1.9829656626983019e-11f,
     1.0967474900693360e-14f,
     0.0f,
    -1.6703459536984179e-22f,
    -4.5995743893035117e-27f,
     0.0f
};

__global__ __launch_bounds__(256)
void cwt_kernel(const float* __restrict__ sig, float* __restrict__ out,
                const int out_size, const int interleaved) {
    const int c = blockIdx.x * blockDim.x + threadIdx.x;   // complex index
    if (c >= NCPLX) return;

    const int n  = c & (SIGLEN - 1);
    const int bs = c >> 12;            // b*NSCALES + s
    const int s  = bs & (NSCALES - 1);
    const int b  = bs >> 5;

    // wl = min(2048, 64 + 4032*s/31) — exact match of the host table, all even.
    const int wl = min(2048, 64 + (4032 * s) / 31);

    const float* __restrict__ sb = sig + b * SIGLEN;
    const int base = n - wl;

    float re = 0.0f, im = 0.0f;
#pragma unroll
    for (int k = 0; k < KTAPS; ++k) {
        const int j = base + k;
        const int jc = j < 0 ? 0 : j;          // address always in [0, SIGLEN)
        float x = sb[jc];                      // upper bound never binds: wl >= 64 > KTAPS
        x = (j < 0) ? 0.0f : x;                // zero the VALUE, not the address
        re = fmaf(WRE[k], x, re);
        im = fmaf(WIM[k], x, im);
    }

    if (interleaved) {
        const int f = 2 * c;
        if (f + 1 < out_size) {                // guarded: never write past out_size floats
            out[f]     = re;
            out[f + 1] = im;
        }
    } else {
        if (c < out_size) {
            out[c] = re;                       // real-part-only layout
        }
    }
}

extern "C" void kernel_launch(void* const* d_in, const int* in_sizes, int n_in,
                              void* d_out, int out_size, void* d_ws, size_t ws_size,
                              hipStream_t stream) {
    const float* sig = (const float*)d_in[0];
    float* out = (float*)d_out;

    const int interleaved = (out_size >= 2 * NCPLX) ? 1 : 0;

    const int block = 256;
    const int grid = (NCPLX + block - 1) / block;   // 2048 blocks

    cwt_kernel<<<grid, block, 0, stream>>>(sig, out, out_size, interleaved);
}